// Round 3
// baseline (9415.894 us; speedup 1.0000x reference)
//
#include <hip/hip_runtime.h>

// ---------------------------------------------------------------------------
// Discriminator: 2-layer ReLU RNN (B=64, T=512, I=256, H=512) + FC(512->1) + sigmoid
// ALL TENSORS FP32 (reference dtype; prior rounds' NaNs were fp32-read-as-bf16).
//
//  K0 transpose  : WT_l = W_hh_l^T  (fp32 [K][N], lane-coalesced scan reads)
//  K1 gemm_proj  : xw0 = x @ W_ih0^T + b_ih0 + b_hh0   -> ws  [T*B, H]
//  K2 rnn_scan<0>: h0[b,t,:] = scan (VALU, W^T streamed from L2)
//  K3 gemm_proj  : xw1 = h0 @ W_ih1^T + b_ih1 + b_hh1  -> ws
//  K4 rnn_scan<1>: scan + fused FC(512->1) + sigmoid   -> d_out [B,T] fp32
// ---------------------------------------------------------------------------

#define T_DIM 512
#define H_DIM 512
#define B_DIM 64

// ---------------------------------------------------------------------------
// 512x512 fp32 transpose: WT[k][n] = W[n][k]
// ---------------------------------------------------------------------------
__global__ __launch_bounds__(1024) void transpose512(
    const float* __restrict__ W, float* __restrict__ WT)
{
    __shared__ float tile[32][33];
    int x = blockIdx.x * 32 + threadIdx.x;
    int y = blockIdx.y * 32 + threadIdx.y;
    tile[threadIdx.y][threadIdx.x] = W[y * 512 + x];
    __syncthreads();
    int xo = blockIdx.y * 32 + threadIdx.x;
    int yo = blockIdx.x * 32 + threadIdx.y;
    WT[yo * 512 + xo] = tile[threadIdx.x][threadIdx.y];
}

// ---------------------------------------------------------------------------
// fp32 projection GEMM: out[r][n] = sum_k A[b,t,k]*W[n,k] + b1[n] + b2[n]
// where r = t*64 + b  (so out is [T][B][H] flat).  A: [B][T][Kin] row-major.
// grid (M/64, 8), block 256; 64x64 tile, 4x4 accum per thread.
// ---------------------------------------------------------------------------
__global__ __launch_bounds__(256) void gemm_proj_f32(
    const float* __restrict__ A,
    const float* __restrict__ W,
    const float* __restrict__ b1,
    const float* __restrict__ b2,
    float* __restrict__ out,
    int Kin)
{
    __shared__ float As[16][68];   // [k][r] (+4 pad)
    __shared__ float Bs[16][68];   // [k][n]

    const int tx = threadIdx.x & 15;    // n quad
    const int ty = threadIdx.x >> 4;    // r quad
    const int r0 = blockIdx.x * 64;
    const int n0 = blockIdx.y * 64;

    float acc[4][4] = {};

    const int rr = threadIdx.x >> 2;         // 0..63 (staging row)
    const int kk4 = (threadIdx.x & 3) * 4;   // 0,4,8,12

    for (int kc = 0; kc < Kin; kc += 16) {
        // stage A tile (64 r x 16 k) and W tile (64 n x 16 k), [k][r/n] layout
        {
            int r = r0 + rr;
            int b = r & 63, t = r >> 6;
            const float* ap = A + (size_t)(b * T_DIM + t) * Kin + kc + kk4;
            float4 av = *(const float4*)ap;
            As[kk4 + 0][rr] = av.x; As[kk4 + 1][rr] = av.y;
            As[kk4 + 2][rr] = av.z; As[kk4 + 3][rr] = av.w;
            const float* wp = W + (size_t)(n0 + rr) * Kin + kc + kk4;
            float4 wv = *(const float4*)wp;
            Bs[kk4 + 0][rr] = wv.x; Bs[kk4 + 1][rr] = wv.y;
            Bs[kk4 + 2][rr] = wv.z; Bs[kk4 + 3][rr] = wv.w;
        }
        __syncthreads();

#pragma unroll
        for (int kk = 0; kk < 16; ++kk) {
            float4 av = *(const float4*)&As[kk][ty * 4];
            float4 bv = *(const float4*)&Bs[kk][tx * 4];
            float a[4] = {av.x, av.y, av.z, av.w};
            float b[4] = {bv.x, bv.y, bv.z, bv.w};
#pragma unroll
            for (int i = 0; i < 4; ++i)
#pragma unroll
                for (int j = 0; j < 4; ++j)
                    acc[i][j] = fmaf(a[i], b[j], acc[i][j]);
        }
        __syncthreads();
    }

    // epilogue: + biases, store
#pragma unroll
    for (int j = 0; j < 4; ++j) {
        int n = n0 + tx * 4 + j;
        float bias = b1[n] + b2[n];
#pragma unroll
        for (int i = 0; i < 4; ++i) {
            int r = r0 + ty * 4 + i;
            out[(size_t)r * H_DIM + n] = acc[i][j] + bias;
        }
    }
}

// ---------------------------------------------------------------------------
// Persistent fp32 scan. grid = 64 (one block per batch element b),
// block = 512 (thread = hidden unit n). h state in LDS; W^T streamed
// (1 MB, L2-resident per XCD). LAYER==1 fuses FC + sigmoid.
// ---------------------------------------------------------------------------
template <int LAYER>
__global__ __launch_bounds__(512) void rnn_scan_f32(
    const float* __restrict__ xw,    // [T*B][H], row r = t*64+b
    const float* __restrict__ WT,    // [K][N] = W_hh^T
    float* __restrict__ hout,        // layer0: [B][T][H]
    const float* __restrict__ wfc,   // layer1: [512]
    const float* __restrict__ bfc,   // layer1: [1]
    float* __restrict__ outp)        // layer1: [B][T]
{
    __shared__ float h[512];
    __shared__ float red[8];

    const int tid  = threadIdx.x;    // n
    const int lane = tid & 63;
    const int w    = tid >> 6;
    const int b    = blockIdx.x;

    h[tid] = 0.f;

    float wfcv = 0.f, bfcv = 0.f;
    if (LAYER == 1) { wfcv = wfc[tid]; bfcv = bfc[0]; }

    const float* wp0 = WT + tid;     // column n of W^T; row stride 512
    __syncthreads();

    for (int t = 0; t < T_DIM; ++t) {
        float acc = xw[(size_t)(t * B_DIM + b) * H_DIM + tid];   // coalesced

        const float* wp = wp0;
#pragma unroll 8
        for (int kc = 0; kc < 128; ++kc) {
            float4 hc = *(const float4*)&h[kc * 4];   // LDS broadcast
            acc = fmaf(hc.x, wp[0],    acc);
            acc = fmaf(hc.y, wp[512],  acc);
            acc = fmaf(hc.z, wp[1024], acc);
            acc = fmaf(hc.w, wp[1536], acc);
            wp += 2048;
        }
        float v = fmaxf(acc, 0.f);

        __syncthreads();             // all reads of h_{t-1} complete
        h[tid] = v;

        if (LAYER == 0) {
            hout[(size_t)(b * T_DIM + t) * H_DIM + tid] = v;   // coalesced
        } else {
            float p = v * wfcv;
#pragma unroll
            for (int s = 1; s < 64; s <<= 1) p += __shfl_xor(p, s);
            if (lane == 0) red[w] = p;
        }
        __syncthreads();             // h_t (+ red) visible

        if (LAYER == 1 && tid == 0) {
            float s = red[0] + red[1] + red[2] + red[3]
                    + red[4] + red[5] + red[6] + red[7] + bfcv;
            outp[b * T_DIM + t] = 1.f / (1.f + __expf(-s));
        }
    }
}

// ---------------------------------------------------------------------------
extern "C" void kernel_launch(void* const* d_in, const int* in_sizes, int n_in,
                              void* d_out, int out_size, void* d_ws, size_t ws_size,
                              hipStream_t stream)
{
    const float* x     = (const float*)d_in[0];
    const float* W_ih0 = (const float*)d_in[1];
    const float* W_hh0 = (const float*)d_in[2];
    const float* b_ih0 = (const float*)d_in[3];
    const float* b_hh0 = (const float*)d_in[4];
    const float* W_ih1 = (const float*)d_in[5];
    const float* W_hh1 = (const float*)d_in[6];
    const float* b_ih1 = (const float*)d_in[7];
    const float* b_hh1 = (const float*)d_in[8];
    const float* W_fc  = (const float*)d_in[9];
    const float* b_fc  = (const float*)d_in[10];

    float* ws  = (float*)d_ws;
    float* xw  = ws;                                      // 67.1 MB  [T*B][H]
    float* h0  = xw + (size_t)T_DIM * B_DIM * H_DIM;      // 67.1 MB  [B][T][H]
    float* WT0 = h0 + (size_t)T_DIM * B_DIM * H_DIM;      // 1 MB
    float* WT1 = WT0 + (size_t)H_DIM * H_DIM;             // 1 MB

    dim3 tb(32, 32);
    transpose512<<<dim3(16, 16), tb, 0, stream>>>(W_hh0, WT0);
    transpose512<<<dim3(16, 16), tb, 0, stream>>>(W_hh1, WT1);

    // layer 0
    gemm_proj_f32<<<dim3((T_DIM * B_DIM) / 64, H_DIM / 64), 256, 0, stream>>>(
        x, W_ih0, b_ih0, b_hh0, xw, 256);
    rnn_scan_f32<0><<<B_DIM, 512, 0, stream>>>(xw, WT0, h0, nullptr, nullptr, nullptr);

    // layer 1
    gemm_proj_f32<<<dim3((T_DIM * B_DIM) / 64, H_DIM / 64), 256, 0, stream>>>(
        h0, W_ih1, b_ih1, b_hh1, xw, 512);
    rnn_scan_f32<1><<<B_DIM, 512, 0, stream>>>(xw, WT1, nullptr, W_fc, b_fc,
                                               (float*)d_out);
}

// Round 4
// 3146.911 us; speedup vs baseline: 2.9921x; 2.9921x over previous
//
#include <hip/hip_runtime.h>

// ---------------------------------------------------------------------------
// 2-layer ReLU RNN (B=64,T=512,I=256,H=512) + FC(512->1) + sigmoid. fp32 I/O.
//
// Scan is per-CU L2-BW-bound at fp32 (1 MB W streamed/step). Fix: W_hh + h in
// fp16 (error budget ~1e-3 << 1.1e-2 threshold), MFMA 16x16x32_f16 w/ fp32
// accum, W CU-resident (192 VGPR/lane + 139 KB LDS). xw stays fp32.
//
//  K0 conv_w_f16 x2 : W_hh -> fp16                       (ws)
//  K1 gemm_proj_f32 : xw0 = x @ W_ih0^T + biases         -> ws [T*B][H] fp32
//  K2 rnn_scan_mfma<0>: scan L0, h0 -> global fp32 [B][T][H]
//  K3 gemm_proj_f32 : xw1 = h0 @ W_ih1^T + biases        -> ws
//  K4 rnn_scan_mfma<1>: scan L1 + fused FC + sigmoid     -> d_out [B][T] fp32
// ---------------------------------------------------------------------------

typedef _Float16 half8 __attribute__((ext_vector_type(8)));
typedef float    f32x4 __attribute__((ext_vector_type(4)));

#define T_DIM 512
#define H_DIM 512
#define B_DIM 64

// ---------------------------------------------------------------------------
__global__ __launch_bounds__(256) void conv_w_f16(
    const float* __restrict__ in, _Float16* __restrict__ out)
{
    int i = (blockIdx.x * 256 + threadIdx.x) * 4;
    float4 v = *(const float4*)(in + i);
    out[i + 0] = (_Float16)v.x;
    out[i + 1] = (_Float16)v.y;
    out[i + 2] = (_Float16)v.z;
    out[i + 3] = (_Float16)v.w;
}

// ---------------------------------------------------------------------------
// fp32 projection GEMM (unchanged from round 3; ~150 us each).
// out[(t*64+b)][n] = sum_k A[b,t,k]*W[n,k] + b1[n] + b2[n]
// ---------------------------------------------------------------------------
__global__ __launch_bounds__(256) void gemm_proj_f32(
    const float* __restrict__ A,
    const float* __restrict__ W,
    const float* __restrict__ b1,
    const float* __restrict__ b2,
    float* __restrict__ out,
    int Kin)
{
    __shared__ float As[16][68];
    __shared__ float Bs[16][68];

    const int tx = threadIdx.x & 15;
    const int ty = threadIdx.x >> 4;
    const int r0 = blockIdx.x * 64;
    const int n0 = blockIdx.y * 64;

    float acc[4][4] = {};

    const int rr  = threadIdx.x >> 2;
    const int kk4 = (threadIdx.x & 3) * 4;

    for (int kc = 0; kc < Kin; kc += 16) {
        {
            int r = r0 + rr;
            int b = r & 63, t = r >> 6;
            float4 av = *(const float4*)(A + (size_t)(b * T_DIM + t) * Kin + kc + kk4);
            As[kk4 + 0][rr] = av.x; As[kk4 + 1][rr] = av.y;
            As[kk4 + 2][rr] = av.z; As[kk4 + 3][rr] = av.w;
            float4 wv = *(const float4*)(W + (size_t)(n0 + rr) * Kin + kc + kk4);
            Bs[kk4 + 0][rr] = wv.x; Bs[kk4 + 1][rr] = wv.y;
            Bs[kk4 + 2][rr] = wv.z; Bs[kk4 + 3][rr] = wv.w;
        }
        __syncthreads();

#pragma unroll
        for (int kk = 0; kk < 16; ++kk) {
            float4 av = *(const float4*)&As[kk][ty * 4];
            float4 bv = *(const float4*)&Bs[kk][tx * 4];
            float a[4] = {av.x, av.y, av.z, av.w};
            float b[4] = {bv.x, bv.y, bv.z, bv.w};
#pragma unroll
            for (int i = 0; i < 4; ++i)
#pragma unroll
                for (int j = 0; j < 4; ++j)
                    acc[i][j] = fmaf(a[i], b[j], acc[i][j]);
        }
        __syncthreads();
    }

#pragma unroll
    for (int j = 0; j < 4; ++j) {
        int n = n0 + tx * 4 + j;
        float bias = b1[n] + b2[n];
#pragma unroll
        for (int i = 0; i < 4; ++i) {
            int r = r0 + ty * 4 + i;
            out[(size_t)r * H_DIM + n] = acc[i][j] + bias;
        }
    }
}

// ---------------------------------------------------------------------------
// Persistent MFMA recurrence. grid=4 (16-batch groups), 512 thr (8 waves).
// Wave w owns n in [w*64, w*64+64) (4 n-tiles of 16x16x32 MFMA).
// W16 resident: k-tiles 0..11 in VGPRs (192/lane), k 384..511 in LDS.
// A-frag: a[m=lane&15][k=q*8+j] ; C/D: col=lane&15, row=q*4+reg.
// ---------------------------------------------------------------------------
template <int LAYER>
__global__ __launch_bounds__(512, 2) void rnn_scan_mfma(
    const float* __restrict__ xw,       // [T*B][H], row r = t*64+b, fp32
    const _Float16* __restrict__ W16,   // [512][512] fp16
    float* __restrict__ hout,           // L0: [B][T][H] fp32
    const float* __restrict__ wfc,      // L1: [512] fp32
    const float* __restrict__ bfc,      // L1: [1]
    float* __restrict__ outp)           // L1: [B][T] fp32
{
    __shared__ _Float16 Wl[512][136];   // k 384..511 (+8 pad) = 139,264 B
    __shared__ _Float16 hbuf[16][520];  // h state fp16 (padded) = 16,640 B

    const int tid  = threadIdx.x;
    const int w    = tid >> 6;
    const int lane = tid & 63;
    const int col  = lane & 15;
    const int q    = lane >> 4;
    const int g    = blockIdx.x;

    // zero h state
    {
        _Float16* hb = &hbuf[0][0];
        for (int i = tid; i < 16 * 520; i += 512) hb[i] = (_Float16)0.f;
    }
    // LDS weights: k 384..511 of every n-row (row tid)
#pragma unroll
    for (int c = 0; c < 16; ++c)
        *(half8*)(&Wl[tid][c * 8]) =
            *(const half8*)(W16 + (size_t)tid * 512 + 384 + c * 8);

    // register weights: k-tiles 0..11 for this wave's 4 n-tiles
    half8 wreg[12][4];
#pragma unroll
    for (int kt = 0; kt < 12; ++kt)
#pragma unroll
        for (int nt = 0; nt < 4; ++nt)
            wreg[kt][nt] = *(const half8*)(
                W16 + (size_t)(w * 64 + nt * 16 + col) * 512 + kt * 32 + q * 8);

    // FC weights (layer 1): thread (fm,fcc) covers h[fm][fcc*16 .. fcc*16+15]
    const int fm  = tid >> 5;
    const int fcc = tid & 31;
    half8 wf0 = {}, wf1 = {};
    float bfcv = 0.f;
    if (LAYER == 1) {
#pragma unroll
        for (int j = 0; j < 8; ++j) {
            wf0[j] = (_Float16)wfc[fcc * 16 + j];
            wf1[j] = (_Float16)wfc[fcc * 16 + 8 + j];
        }
        bfcv = bfc[0];
    }

    __syncthreads();

    for (int t = 0; t < T_DIM; ++t) {
        // xw values this lane owns (C/D positions), fp32 scalar loads
        const float* xwt = xw + ((size_t)t * B_DIM + g * 16) * H_DIM;
        float xv[4][4];
#pragma unroll
        for (int nt = 0; nt < 4; ++nt)
#pragma unroll
            for (int r = 0; r < 4; ++r)
                xv[nt][r] = xwt[(size_t)(q * 4 + r) * H_DIM + w * 64 + nt * 16 + col];

        f32x4 acc[4] = {};
#pragma unroll
        for (int kt = 0; kt < 16; ++kt) {
            half8 a = *(const half8*)(&hbuf[col][kt * 32 + q * 8]);
#pragma unroll
            for (int nt = 0; nt < 4; ++nt) {
                half8 b;
                if (kt < 12) b = wreg[kt][nt];
                else         b = *(const half8*)(&Wl[w * 64 + nt * 16 + col][(kt - 12) * 32 + q * 8]);
                acc[nt] = __builtin_amdgcn_mfma_f32_16x16x32_f16(a, b, acc[nt], 0, 0, 0);
            }
        }
        __syncthreads();   // all reads of h_{t-1} complete

        // h_t = relu(acc + xw); store fp16 at owner positions
#pragma unroll
        for (int nt = 0; nt < 4; ++nt)
#pragma unroll
            for (int r = 0; r < 4; ++r) {
                float v = fmaxf(acc[nt][r] + xv[nt][r], 0.f);
                hbuf[q * 4 + r][w * 64 + nt * 16 + col] = (_Float16)v;
            }
        __syncthreads();   // h_t visible

        if (LAYER == 0) {
            // h_t -> global fp32 [B][T][H]
            int m = tid >> 5, c = tid & 31;
            half8 v0 = *(const half8*)(&hbuf[m][c * 16]);
            half8 v1 = *(const half8*)(&hbuf[m][c * 16 + 8]);
            float* hp = hout + ((size_t)(g * 16 + m) * T_DIM + t) * H_DIM + c * 16;
            float4 o0 = {(float)v0[0], (float)v0[1], (float)v0[2], (float)v0[3]};
            float4 o1 = {(float)v0[4], (float)v0[5], (float)v0[6], (float)v0[7]};
            float4 o2 = {(float)v1[0], (float)v1[1], (float)v1[2], (float)v1[3]};
            float4 o3 = {(float)v1[4], (float)v1[5], (float)v1[6], (float)v1[7]};
            *(float4*)(hp + 0)  = o0;
            *(float4*)(hp + 4)  = o1;
            *(float4*)(hp + 8)  = o2;
            *(float4*)(hp + 12) = o3;
        } else {
            // fused FC + sigmoid
            half8 v0 = *(const half8*)(&hbuf[fm][fcc * 16]);
            half8 v1 = *(const half8*)(&hbuf[fm][fcc * 16 + 8]);
            float p = 0.f;
#pragma unroll
            for (int j = 0; j < 8; ++j)
                p += (float)v0[j] * (float)wf0[j] + (float)v1[j] * (float)wf1[j];
#pragma unroll
            for (int s = 1; s < 32; s <<= 1) p += __shfl_xor(p, s);
            if (fcc == 0) {
                float lg = p + bfcv;
                outp[(size_t)(g * 16 + fm) * T_DIM + t] = 1.f / (1.f + __expf(-lg));
            }
        }
    }
}

// ---------------------------------------------------------------------------
extern "C" void kernel_launch(void* const* d_in, const int* in_sizes, int n_in,
                              void* d_out, int out_size, void* d_ws, size_t ws_size,
                              hipStream_t stream)
{
    const float* x     = (const float*)d_in[0];
    const float* W_ih0 = (const float*)d_in[1];
    const float* W_hh0 = (const float*)d_in[2];
    const float* b_ih0 = (const float*)d_in[3];
    const float* b_hh0 = (const float*)d_in[4];
    const float* W_ih1 = (const float*)d_in[5];
    const float* W_hh1 = (const float*)d_in[6];
    const float* b_ih1 = (const float*)d_in[7];
    const float* b_hh1 = (const float*)d_in[8];
    const float* W_fc  = (const float*)d_in[9];
    const float* b_fc  = (const float*)d_in[10];

    float* ws = (float*)d_ws;
    float* xw = ws;                                       // 67.1 MB [T*B][H]
    float* h0 = xw + (size_t)T_DIM * B_DIM * H_DIM;       // 67.1 MB [B][T][H]
    _Float16* W16_0 = (_Float16*)(h0 + (size_t)T_DIM * B_DIM * H_DIM);  // 512 KB
    _Float16* W16_1 = W16_0 + (size_t)H_DIM * H_DIM;                    // 512 KB

    conv_w_f16<<<256, 256, 0, stream>>>(W_hh0, W16_0);
    conv_w_f16<<<256, 256, 0, stream>>>(W_hh1, W16_1);

    dim3 gp((T_DIM * B_DIM) / 64, H_DIM / 64);

    // layer 0
    gemm_proj_f32<<<gp, 256, 0, stream>>>(x, W_ih0, b_ih0, b_hh0, xw, 256);
    rnn_scan_mfma<0><<<4, 512, 0, stream>>>(xw, W16_0, h0, nullptr, nullptr, nullptr);

    // layer 1
    gemm_proj_f32<<<gp, 256, 0, stream>>>(h0, W_ih1, b_ih1, b_hh1, xw, 512);
    rnn_scan_mfma<1><<<4, 512, 0, stream>>>(xw, W16_1, nullptr, W_fc, b_fc,
                                            (float*)d_out);
}